// Round 6
// baseline (353.638 us; speedup 1.0000x reference)
//
#include <hip/hip_runtime.h>

typedef _Float16 half8 __attribute__((ext_vector_type(8)));
typedef float f32x4 __attribute__((ext_vector_type(4)));

#define NB 2
#define LS 4800
#define CCH 256
#define W0 80
#define W1 80
#define THRV 0.2f
#define SQS 0.19764235376052370f   // sqrt(1/(C*TEMP)) = sqrt(1/25.6)

#define TN  38         // col tiles (BN=128) -> padded 4864
#define TNM 19         // row tiles (BM=256) -> padded 4864
#define PADL 4864
#define NROWB 32       // rows per stream_conf block
#define NPB   150      // col-max partials per image (4800/32)

// ---- ws float offsets ----
#define OF_RST  0                       // float2[NB][LS] row (M, 1/S)
#define OF_CST  19200                   // float2[NB][LS] col (M, 1/S)
#define OF_RWM  38400                   // [NB*LS] conf row max
#define OF_CAND 48000                   // [NB*LS] (int) argmax col of conf row max
#define OF_CLM  57600                   // [NB*LS] conf col max
#define OF_PROW 67200                   // pass1: float2 [NB][PADL][TN] row partials (m,s)
#define OF_PCOL (67200 + 739328)        // pass1: float2 [NB][PADL][TNM] col partials
#define OF_CMAXP OF_PROW                // stream: float [NB][NPB][LS] colmax partials (reuses dead pass1 region)
#define OF_AH   (67200 + 2*739328)      // _Float16 [NB][LS][CCH]
#define OF_BH   (OF_AH + 1228800)

// ---- out float offsets ----
#define O_MASKV 46080000ull
#define O_JIDS  46089600ull
#define O_MKPT  46099200ull
#define O_MCONF 46118400ull

__device__ __forceinline__ void load_lds16(const void* g, void* l) {
    __builtin_amdgcn_global_load_lds((const __attribute__((address_space(1))) void*)g,
                                     (__attribute__((address_space(3))) void*)l, 16, 0, 0);
}

// XCD-aware bijective remap (m204 form: NWG=1444, q=180, r=4).
__device__ __forceinline__ void swizzle_ids(int& n, int& by, int& bx) {
    const int orig = ((int)blockIdx.z * TNM + (int)blockIdx.y) * TN + (int)blockIdx.x;
    const int xcd = orig & 7, t = orig >> 3;
    const int wg = (xcd < 4 ? xcd * 181 : 724 + (xcd - 4) * 180) + t;
    n = wg / (TN * TNM);
    const int rem = wg % (TN * TNM);
    by = rem / TN; bx = rem % TN;
}

// --------------------------------------------------------- f32 -> f16 cast --
__global__ __launch_bounds__(256) void conv_half(const float* __restrict__ A,
                                                 const float* __restrict__ B,
                                                 float* __restrict__ ws) {
    const int which = blockIdx.y;
    const float* src = which ? B : A;
    _Float16* dst = (_Float16*)(ws + (which ? OF_BH : OF_AH));
    const int idx = blockIdx.x * 256 + threadIdx.x;   // float4 index, 614400 total
    const float4 v = ((const float4*)src)[idx];
    union { _Float16 h[4]; uint2 u; } p;
    p.h[0] = (_Float16)(v.x * SQS);
    p.h[1] = (_Float16)(v.y * SQS);
    p.h[2] = (_Float16)(v.z * SQS);
    p.h[3] = (_Float16)(v.w * SQS);
    ((uint2*)dst)[idx] = p.u;
}

// ------- shared MFMA K-loop: 256x128 tile, 8 waves, BK=32, double-buffered --
// (unchanged from r5; conflict-free swizzled LDS, linear global_load_lds dest)
__device__ __forceinline__ void gemm_core(const _Float16* __restrict__ Ah,
                                          const _Float16* __restrict__ Bh,
                                          _Float16* smA, _Float16* smB,   // [2][8192], [2][4096]
                                          const int bx, const int by,
                                          const int tid, f32x4 (&acc)[4][4]) {
    const int lane = tid & 63, w = tid >> 6;
    const int wx = w & 1, wy = w >> 1;
    const int m = lane & 15, quad = lane >> 4;
    const int rr = lane >> 2;                       // 0..15 row within chunk
    const int q = (lane & 3) ^ ((lane >> 3) & 3);   // swizzled k-group 0..3

    const _Float16* ga[2];
    const _Float16* gb0;
    {
#pragma unroll
        for (int i = 0; i < 2; i++) {
            const int c = w * 2 + i;
            int gra = by * 256 + c * 16 + rr; gra = gra < LS ? gra : LS - 1;
            ga[i] = Ah + (size_t)gra * CCH + q * 8;
        }
        int grb = bx * 128 + w * 16 + rr; grb = grb < LS ? grb : LS - 1;
        gb0 = Bh + (size_t)grb * CCH + q * 8;
    }

#pragma unroll
    for (int i = 0; i < 2; i++) load_lds16(ga[i], &smA[(w * 2 + i) * 512]);
    load_lds16(gb0, &smB[w * 512]);

    for (int kt = 0; kt < 8; kt++) {
        __syncthreads();                 // drains vmcnt: buf[cur] ready
        const int curA = (kt & 1) * 8192, curB = (kt & 1) * 4096;
        if (kt < 7) {                    // prefetch kt+1 into other buffer
            const int ko = (kt + 1) * 32;
#pragma unroll
            for (int i = 0; i < 2; i++)
                load_lds16(ga[i] + ko, &smA[(8192 - curA) + (w * 2 + i) * 512]);
            load_lds16(gb0 + ko, &smB[(4096 - curB) + w * 512]);
        }
        half8 Af[4], Bf[4];
#pragma unroll
        for (int a = 0; a < 4; a++) {
            const int rl = wy * 64 + a * 16 + m;
            const int sl = rl * 4 + (quad ^ ((rl >> 1) & 3));
            Af[a] = *(const half8*)&smA[curA + sl * 8];
        }
#pragma unroll
        for (int b = 0; b < 4; b++) {
            const int cl = wx * 64 + b * 16 + m;
            const int sl = cl * 4 + (quad ^ ((cl >> 1) & 3));
            Bf[b] = *(const half8*)&smB[curB + sl * 8];
        }
#pragma unroll
        for (int a = 0; a < 4; a++)
#pragma unroll
            for (int b = 0; b < 4; b++)
                acc[a][b] = __builtin_amdgcn_mfma_f32_16x16x32_f16(Af[a], Bf[b], acc[a][b], 0, 0, 0);
    }
    __syncthreads();   // all ds_reads consumed -> union storage reusable
}

// ---- single GEMM pass: write sim f32 (default-cached -> L3) + stats partials
__global__ __launch_bounds__(512, 4) void gemm_sim(float* __restrict__ out,
                                                   float* __restrict__ ws) {
    __shared__ __align__(16) union {
        struct { _Float16 A[2][8192]; _Float16 B[2][4096]; } st;   // 48KB
        struct { float rs[256][2][2]; float cs[128][4][2]; } red;  // 8KB
    } sm;
    int n, by, bx;
    swizzle_ids(n, by, bx);
    const _Float16* Ah = (const _Float16*)(ws + OF_AH) + (size_t)n * LS * CCH;
    const _Float16* Bh = (const _Float16*)(ws + OF_BH) + (size_t)n * LS * CCH;
    const int tid = threadIdx.x;
    const int lane = tid & 63, w = tid >> 6;
    const int wx = w & 1, wy = w >> 1;
    const int m = lane & 15, quad = lane >> 4;

    f32x4 acc[4][4];
    {
        f32x4 z = {0.f, 0.f, 0.f, 0.f};
#pragma unroll
        for (int a = 0; a < 4; a++)
#pragma unroll
            for (int b = 0; b < 4; b++) acc[a][b] = z;
    }
    gemm_core(Ah, Bh, &sm.st.A[0][0], &sm.st.B[0][0], bx, by, tid, acc);

    const int l0 = by * 256, s0 = bx * 128;
    bool bval[4]; int gc4[4];
#pragma unroll
    for (int b = 0; b < 4; b++) {
        gc4[b] = s0 + wx * 64 + b * 16 + m;
        bval[b] = gc4[b] < LS;
    }

    // ---- store sim (regular stores: keep in L3 for stream_conf) ----
    float* On = out + (size_t)n * LS * LS;
#pragma unroll
    for (int a = 0; a < 4; a++)
#pragma unroll
        for (int reg = 0; reg < 4; reg++) {
            const int gr = l0 + wy * 64 + a * 16 + quad * 4 + reg;
            if (gr < LS) {
#pragma unroll
                for (int b = 0; b < 4; b++)
                    if (bval[b]) On[(size_t)gr * LS + gc4[b]] = acc[a][b][reg];
            }
        }

    // wave-wide reference max over valid elements
    float T = -1e30f;
#pragma unroll
    for (int a = 0; a < 4; a++)
#pragma unroll
        for (int reg = 0; reg < 4; reg++) {
            if ((l0 + wy * 64 + a * 16 + quad * 4 + reg) < LS) {
#pragma unroll
                for (int b = 0; b < 4; b++)
                    if (bval[b]) T = fmaxf(T, acc[a][b][reg]);
            }
        }
#pragma unroll
    for (int d = 1; d < 64; d <<= 1) T = fmaxf(T, __shfl_xor(T, d, 64));

    // exponentials in place (invalid -> 0)
#pragma unroll
    for (int a = 0; a < 4; a++)
#pragma unroll
        for (int reg = 0; reg < 4; reg++) {
            const bool rv = (l0 + wy * 64 + a * 16 + quad * 4 + reg) < LS;
#pragma unroll
            for (int b = 0; b < 4; b++)
                acc[a][b][reg] = (rv && bval[b]) ? __expf(acc[a][b][reg] - T) : 0.f;
        }

    // row sums: per (a,reg) sum over b then 16 m-lanes
#pragma unroll
    for (int a = 0; a < 4; a++)
#pragma unroll
        for (int reg = 0; reg < 4; reg++) {
            float s = acc[a][0][reg] + acc[a][1][reg] + acc[a][2][reg] + acc[a][3][reg];
#pragma unroll
            for (int d = 1; d < 16; d <<= 1) s += __shfl_xor(s, d, 64);
            if (m == 0) {
                const int rl = wy * 64 + a * 16 + quad * 4 + reg;
                sm.red.rs[rl][wx][0] = T; sm.red.rs[rl][wx][1] = s;
            }
        }
    // col sums: per b sum over (a,reg) then quads
#pragma unroll
    for (int b = 0; b < 4; b++) {
        float s = 0.f;
#pragma unroll
        for (int a = 0; a < 4; a++)
#pragma unroll
            for (int reg = 0; reg < 4; reg++) s += acc[a][b][reg];
        s += __shfl_xor(s, 16, 64);
        s += __shfl_xor(s, 32, 64);
        if (quad == 0) {
            const int cl = wx * 64 + b * 16 + m;
            sm.red.cs[cl][wy][0] = T; sm.red.cs[cl][wy][1] = s;
        }
    }
    __syncthreads();
    if (tid < 256) {
        const float m0 = sm.red.rs[tid][0][0], v0 = sm.red.rs[tid][0][1];
        const float m1 = sm.red.rs[tid][1][0], v1 = sm.red.rs[tid][1][1];
        const float nm = fmaxf(m0, m1);
        const float s = v0 * __expf(m0 - nm) + v1 * __expf(m1 - nm);
        ((float2*)(ws + OF_PROW))[((size_t)n * PADL + l0 + tid) * TN + bx] = make_float2(nm, s);
    } else if (tid < 384) {
        const int t = tid - 256;
        float M = sm.red.cs[t][0][0], S = sm.red.cs[t][0][1];
#pragma unroll
        for (int k = 1; k < 4; k++) {
            const float mo = sm.red.cs[t][k][0], so = sm.red.cs[t][k][1];
            const float nm = fmaxf(M, mo);
            S = S * __expf(M - nm) + so * __expf(mo - nm);
            M = nm;
        }
        ((float2*)(ws + OF_PCOL))[((size_t)n * PADL + s0 + t) * TNM + by] = make_float2(M, S);
    }
}

// -------------------------------------------------- combine partials --------
__global__ __launch_bounds__(256) void combine_stats(float* __restrict__ ws) {
    const int idx = blockIdx.x * 256 + threadIdx.x;   // 19200 total
    const int half_ = idx >= 9600;
    const int i = idx - half_ * 9600;
    const int n = i / LS, r = i % LS;
    float M = -1e30f, S = 0.f;
    if (!half_) {
        const float2* P = (const float2*)(ws + OF_PROW) + ((size_t)n * PADL + r) * TN;
        for (int b = 0; b < TN; b++) {
            const float2 p = P[b];
            const float nm = fmaxf(M, p.x);
            S = S * __expf(M - nm) + p.y * __expf(p.x - nm);
            M = nm;
        }
        ((float2*)(ws + OF_RST))[n * LS + r] = make_float2(M, 1.0f / S);
    } else {
        const float2* P = (const float2*)(ws + OF_PCOL) + ((size_t)n * PADL + r) * TNM;
        for (int b = 0; b < TNM; b++) {
            const float2 p = P[b];
            const float nm = fmaxf(M, p.x);
            S = S * __expf(M - nm) + p.y * __expf(p.x - nm);
            M = nm;
        }
        ((float2*)(ws + OF_CST))[n * LS + r] = make_float2(M, 1.0f / S);
    }
}

// ---- streaming pass: sim (L3-resident) -> conf in place, fused row argmax
// (block owns 32 rows exclusively -> direct rwm/cand write) + colmax partials.
__global__ __launch_bounds__(256) void stream_conf(float* __restrict__ out,
                                                   float* __restrict__ ws) {
    const int n = blockIdx.y, rb = blockIdx.x;      // rb < NPB (150)
    const int tid = threadIdx.x;
    __shared__ float Lv[16][256];
    __shared__ int   Li[16][256];
    __shared__ float Mv[16][16];
    __shared__ int   Mi[16][16];

    float cmv[19], csiv[19], cmax[19];
#pragma unroll
    for (int j = 0; j < 19; j++) {
        const int s = tid + j * 256;
        cmax[j] = 0.f;
        if (s < LS) {
            const float2 v = ((const float2*)(ws + OF_CST))[n * LS + s];
            cmv[j] = v.x; csiv[j] = v.y;
        } else { cmv[j] = 0.f; csiv[j] = 0.f; }
    }

    float* base = out + ((size_t)n * LS + rb * NROWB) * LS;
    for (int ch = 0; ch < 2; ch++) {
        for (int r16 = 0; r16 < 16; r16++) {
            const int r = ch * 16 + r16;
            const float2 rs = ((const float2*)(ws + OF_RST))[n * LS + rb * NROWB + r];
            float* row = base + (size_t)r * LS;
            float lmax = -1.f; int lidx = 0;
#pragma unroll
            for (int j = 0; j < 19; j++) {
                const int s = tid + j * 256;
                if (s < LS) {
                    const float x = row[s];
                    const float c = __expf(2.f * x - rs.x - cmv[j]) * (rs.y * csiv[j]);
                    __builtin_nontemporal_store(c, &row[s]);   // no-allocate: don't evict sim from L3
                    cmax[j] = fmaxf(cmax[j], c);
                    if (c > lmax) { lmax = c; lidx = s; }
                }
            }
            Lv[r16][tid] = lmax; Li[r16][tid] = lidx;
        }
        __syncthreads();
        {
            const int r = tid >> 4, p = tid & 15;
            float bv = -2.f; int bi = 0;
            for (int k = 0; k < 16; k++) {
                const float v = Lv[r][p * 16 + k]; const int ii = Li[r][p * 16 + k];
                if (v > bv || (v == bv && ii < bi)) { bv = v; bi = ii; }
            }
            Mv[r][p] = bv; Mi[r][p] = bi;
        }
        __syncthreads();
        if (tid < 16) {
            float bv = -2.f; int bi = 0;
            for (int p = 0; p < 16; p++) {
                const float v = Mv[tid][p]; const int ii = Mi[tid][p];
                if (v > bv || (v == bv && ii < bi)) { bv = v; bi = ii; }
            }
            const int gr = n * LS + rb * NROWB + ch * 16 + tid;
            ws[OF_RWM + gr] = bv;
            ((int*)ws)[OF_CAND + gr] = bi;
        }
        __syncthreads();   // Lv/Li reused next chunk
    }

    // coalesced colmax partials: [n][rb][col]
#pragma unroll
    for (int j = 0; j < 19; j++) {
        const int s = tid + j * 256;
        if (s < LS) ws[OF_CMAXP + ((size_t)n * NPB + rb) * LS + s] = cmax[j];
    }
}

// ------------------------------------------- combine col-max partials -------
__global__ __launch_bounds__(256) void combine_col(float* __restrict__ ws) {
    const int idx = blockIdx.x * 256 + threadIdx.x;   // 9600 total
    if (idx >= NB * LS) return;
    const int n = idx / LS, c = idx % LS;
    const float* P = ws + OF_CMAXP + (size_t)n * NPB * LS + c;
    float v = -2.f;
#pragma unroll 4
    for (int p = 0; p < NPB; p++) v = fmaxf(v, P[(size_t)p * LS]);
    ws[OF_CLM + idx] = v;
}

// ------------------------------------------------------------- matching -----
__global__ __launch_bounds__(256) void match_pass(const float* __restrict__ ws,
                                                  float* __restrict__ out) {
    const int idx = blockIdx.x * 256 + threadIdx.x;
    if (idx >= NB * LS) return;
    const int n = idx / LS, l = idx % LS;
    const float rwm = ws[OF_RWM + idx];
    const int cand = ((const int*)ws)[OF_CAND + idx];
    const float clm = ws[OF_CLM + n * LS + cand];
    const int y0 = l / W0, x0 = l % W0;
    const int y1 = cand / W1, x1 = cand % W1;
    const bool b0 = (y0 >= 2 && y0 < 58 && x0 >= 2 && x0 < 78);
    const bool b1 = (y1 >= 2 && y1 < 58 && x1 >= 2 && x1 < 78);
    const bool matched = (rwm > THRV) && b0 && b1 && (rwm == clm);
    const int j = matched ? cand : 0;
    out[O_MASKV + idx] = matched ? 1.f : 0.f;
    out[O_JIDS + idx] = (float)j;
    out[O_MKPT + (size_t)idx * 2 + 0] = (float)(j % W1);
    out[O_MKPT + (size_t)idx * 2 + 1] = (float)(j / W1);
    out[O_MCONF + idx] = matched ? rwm : 0.f;
}

// -------------------------------------------------------------- launch ------
extern "C" void kernel_launch(void* const* d_in, const int* in_sizes, int n_in,
                              void* d_out, int out_size, void* d_ws, size_t ws_size,
                              hipStream_t stream) {
    const float* f0 = (const float*)d_in[0];
    const float* f1 = (const float*)d_in[1];
    float* out = (float*)d_out;
    float* ws = (float*)d_ws;

    conv_half<<<dim3(2400, 2), 256, 0, stream>>>(f0, f1, ws);
    gemm_sim<<<dim3(TN, TNM, NB), 512, 0, stream>>>(out, ws);
    combine_stats<<<75, 256, 0, stream>>>(ws);
    stream_conf<<<dim3(NPB, NB), 256, 0, stream>>>(out, ws);
    combine_col<<<38, 256, 0, stream>>>(ws);
    match_pass<<<38, 256, 0, stream>>>(ws, out);
}

// Round 7
// 301.688 us; speedup vs baseline: 1.1722x; 1.1722x over previous
//
#include <hip/hip_runtime.h>

typedef _Float16 half8 __attribute__((ext_vector_type(8)));
typedef float f32x4 __attribute__((ext_vector_type(4)));

#define NB 2
#define LS 4800
#define CCH 256
#define W0 80
#define W1 80
#define THRV 0.2f
#define SQS 0.19764235376052370f   // sqrt(1/(C*TEMP)) = sqrt(1/25.6)

#define TN 38          // tiles per dim (128x128) -> padded 4864
#define PADL 4864
#define NWG (TN * TN * NB)          // 2888 = 8 * 361
#define CPX (NWG / 8)               // 361 blocks per XCD chunk

// ---- ws float offsets (16.01 MB total, unchanged from r4) ----
#define OF_RST  0                       // float2[NB][LS] row (M, 1/S)
#define OF_CST  19200                   // float2[NB][LS] col (M, 1/S)
#define OF_RWM  38400                   // [NB*LS] conf row max
#define OF_CAND 48000                   // [NB*LS] (int) argmax col of conf row max
#define OF_CLM  57600                   // [NB*LS] conf col max
#define OF_PROW 67200                   // float2 [NB][PADL][TN] row partials
#define OF_PCOL (67200 + 739328)        // float2 [NB][PADL][TN] col partials (pass2: float)
#define OF_AH   (67200 + 2*739328)      // _Float16 [NB][LS][CCH]
#define OF_BH   (OF_AH + 1228800)

// ---- out float offsets ----
#define O_MASKV 46080000ull
#define O_JIDS  46089600ull
#define O_MKPT  46099200ull
#define O_MCONF 46118400ull

__device__ __forceinline__ void load_lds16(const void* g, void* l) {
    __builtin_amdgcn_global_load_lds((const __attribute__((address_space(1))) void*)g,
                                     (__attribute__((address_space(3))) void*)l, 16, 0, 0);
}

// XCD-aware bijective remap: each XCD owns 361 consecutive tiles.
__device__ __forceinline__ void swizzle_ids(int& n, int& by, int& bx) {
    const int orig = ((int)blockIdx.z * TN + (int)blockIdx.y) * TN + (int)blockIdx.x;
    const int wg = (orig & 7) * CPX + (orig >> 3);
    n = wg / (TN * TN);
    const int rem = wg % (TN * TN);
    by = rem / TN; bx = rem % TN;
}

// --------------------------------------------------------- f32 -> f16 cast --
__global__ __launch_bounds__(256) void conv_half(const float* __restrict__ A,
                                                 const float* __restrict__ B,
                                                 float* __restrict__ ws) {
    const int which = blockIdx.y;
    const float* src = which ? B : A;
    _Float16* dst = (_Float16*)(ws + (which ? OF_BH : OF_AH));
    const int idx = blockIdx.x * 256 + threadIdx.x;   // float4 index, 614400 total
    const float4 v = ((const float4*)src)[idx];
    union { _Float16 h[4]; uint2 u; } p;
    p.h[0] = (_Float16)(v.x * SQS);
    p.h[1] = (_Float16)(v.y * SQS);
    p.h[2] = (_Float16)(v.z * SQS);
    p.h[3] = (_Float16)(v.w * SQS);
    ((uint2*)dst)[idx] = p.u;
}

// ---- MFMA K-loop: 128x128 tile, 8 WAVES (512 thr), BK=32, dbuf 32KB --------
// acc[2][4] = 32 regs/thread (half of the 4-wave version) -> target 24
// waves/CU occupancy. Per kt each thread stages exactly 1 A-load + 1 B-load.
// LDS slice: slot(row,q) = row*4 + (q ^ ((row>>1)&3)) (conflict-free, r4);
// staging: lane L of chunk w -> row=w*16+(L>>2), q=(L&3)^((L>>3)&3).
__device__ __forceinline__ void gemm_core(const _Float16* __restrict__ Ah,
                                          const _Float16* __restrict__ Bh,
                                          _Float16* smA, _Float16* smB,   // each [2][4096]
                                          const int bx, const int by,
                                          const int tid, f32x4 (&acc)[2][4]) {
    const int lane = tid & 63, w = tid >> 6;        // w 0..7
    const int wx = w & 1, wy = w >> 1;              // wy 0..3
    const int m = lane & 15, quad = lane >> 4;
    const int rr = lane >> 2;                       // 0..15 row within chunk
    const int q = (lane & 3) ^ ((lane >> 3) & 3);   // swizzled k-group 0..3

    int gra = by * 128 + w * 16 + rr; gra = gra < LS ? gra : LS - 1;
    int grb = bx * 128 + w * 16 + rr; grb = grb < LS ? grb : LS - 1;
    const _Float16* ga = Ah + (size_t)gra * CCH + q * 8;
    const _Float16* gb = Bh + (size_t)grb * CCH + q * 8;

    // prologue: stage kt=0 into buffer 0
    load_lds16(ga, &smA[w * 512]);
    load_lds16(gb, &smB[w * 512]);

    for (int kt = 0; kt < 8; kt++) {
        __syncthreads();                 // drains vmcnt: buf[cur] ready
        const int cur = (kt & 1) * 4096;
        if (kt < 7) {                    // prefetch kt+1 into other buffer
            const int ko = (kt + 1) * 32;
            const int nxt = 4096 - cur;
            load_lds16(ga + ko, &smA[nxt + w * 512]);
            load_lds16(gb + ko, &smB[nxt + w * 512]);
        }
        half8 Af[2], Bf[4];
#pragma unroll
        for (int a = 0; a < 2; a++) {
            const int rl = wy * 32 + a * 16 + m;
            const int sl = rl * 4 + (quad ^ ((rl >> 1) & 3));
            Af[a] = *(const half8*)&smA[cur + sl * 8];
        }
#pragma unroll
        for (int b = 0; b < 4; b++) {
            const int cl = wx * 64 + b * 16 + m;
            const int sl = cl * 4 + (quad ^ ((cl >> 1) & 3));
            Bf[b] = *(const half8*)&smB[cur + sl * 8];
        }
#pragma unroll
        for (int a = 0; a < 2; a++)
#pragma unroll
            for (int b = 0; b < 4; b++)
                acc[a][b] = __builtin_amdgcn_mfma_f32_16x16x32_f16(Af[a], Bf[b], acc[a][b], 0, 0, 0);
    }
    __syncthreads();   // all ds_reads consumed -> union storage reusable
}

// ------------------------- pass 1: stats-only GEMM (no sim materialization) -
__global__ __launch_bounds__(512, 6) void gemm_stats(float* __restrict__ ws) {
    __shared__ __align__(16) union {
        struct { _Float16 A[2][4096]; _Float16 B[2][4096]; } st;  // 32KB
        struct { float rs[128][2][2]; float cs[128][4][2]; } red; // 6KB
    } sm;
    int n, by, bx;
    swizzle_ids(n, by, bx);
    const _Float16* Ah = (const _Float16*)(ws + OF_AH) + (size_t)n * LS * CCH;
    const _Float16* Bh = (const _Float16*)(ws + OF_BH) + (size_t)n * LS * CCH;
    const int tid = threadIdx.x;
    const int lane = tid & 63, w = tid >> 6;
    const int wx = w & 1, wy = w >> 1;
    const int m = lane & 15, quad = lane >> 4;

    f32x4 acc[2][4];
    {
        f32x4 z = {0.f, 0.f, 0.f, 0.f};
#pragma unroll
        for (int a = 0; a < 2; a++)
#pragma unroll
            for (int b = 0; b < 4; b++) acc[a][b] = z;
    }
    gemm_core(Ah, Bh, &sm.st.A[0][0], &sm.st.B[0][0], bx, by, tid, acc);

    const int l0 = by * 128, s0 = bx * 128;
    const bool full = (by < 37) & (bx < 37);

    float T = -1e30f;
    if (full) {
#pragma unroll
        for (int a = 0; a < 2; a++)
#pragma unroll
            for (int reg = 0; reg < 4; reg++)
#pragma unroll
                for (int b = 0; b < 4; b++) T = fmaxf(T, acc[a][b][reg]);
    } else {
        bool bval[4];
#pragma unroll
        for (int b = 0; b < 4; b++) bval[b] = (s0 + wx * 64 + b * 16 + m) < LS;
#pragma unroll
        for (int a = 0; a < 2; a++)
#pragma unroll
            for (int reg = 0; reg < 4; reg++) {
                if ((l0 + wy * 32 + a * 16 + quad * 4 + reg) < LS) {
#pragma unroll
                    for (int b = 0; b < 4; b++)
                        if (bval[b]) T = fmaxf(T, acc[a][b][reg]);
                }
            }
    }
#pragma unroll
    for (int d = 1; d < 64; d <<= 1) T = fmaxf(T, __shfl_xor(T, d, 64));

    // exponentials in place (invalid -> 0)
    if (full) {
#pragma unroll
        for (int a = 0; a < 2; a++)
#pragma unroll
            for (int reg = 0; reg < 4; reg++)
#pragma unroll
                for (int b = 0; b < 4; b++)
                    acc[a][b][reg] = __expf(acc[a][b][reg] - T);
    } else {
        bool bval[4];
#pragma unroll
        for (int b = 0; b < 4; b++) bval[b] = (s0 + wx * 64 + b * 16 + m) < LS;
#pragma unroll
        for (int a = 0; a < 2; a++)
#pragma unroll
            for (int reg = 0; reg < 4; reg++) {
                const bool rv = (l0 + wy * 32 + a * 16 + quad * 4 + reg) < LS;
#pragma unroll
                for (int b = 0; b < 4; b++)
                    acc[a][b][reg] = (rv && bval[b]) ? __expf(acc[a][b][reg] - T) : 0.f;
            }
    }

    // row sums: per (a,reg) sum over b then 16 m-lanes
#pragma unroll
    for (int a = 0; a < 2; a++)
#pragma unroll
        for (int reg = 0; reg < 4; reg++) {
            float s = acc[a][0][reg] + acc[a][1][reg] + acc[a][2][reg] + acc[a][3][reg];
#pragma unroll
            for (int d = 1; d < 16; d <<= 1) s += __shfl_xor(s, d, 64);
            if (m == 0) {
                const int rl = wy * 32 + a * 16 + quad * 4 + reg;
                sm.red.rs[rl][wx][0] = T; sm.red.rs[rl][wx][1] = s;
            }
        }
    // col sums: per b sum over (a,reg) then quads
#pragma unroll
    for (int b = 0; b < 4; b++) {
        float s = 0.f;
#pragma unroll
        for (int a = 0; a < 2; a++)
#pragma unroll
            for (int reg = 0; reg < 4; reg++) s += acc[a][b][reg];
        s += __shfl_xor(s, 16, 64);
        s += __shfl_xor(s, 32, 64);
        if (quad == 0) {
            const int cl = wx * 64 + b * 16 + m;
            sm.red.cs[cl][wy][0] = T; sm.red.cs[cl][wy][1] = s;
        }
    }
    __syncthreads();
    if (tid < 128) {
        const float m0 = sm.red.rs[tid][0][0], v0 = sm.red.rs[tid][0][1];
        const float m1 = sm.red.rs[tid][1][0], v1 = sm.red.rs[tid][1][1];
        const float nm = fmaxf(m0, m1);
        const float s = v0 * __expf(m0 - nm) + v1 * __expf(m1 - nm);
        ((float2*)(ws + OF_PROW))[((size_t)n * PADL + l0 + tid) * TN + bx] = make_float2(nm, s);
    } else if (tid < 256) {
        const int t = tid - 128;
        float M = sm.red.cs[t][0][0], S = sm.red.cs[t][0][1];
#pragma unroll
        for (int k = 1; k < 4; k++) {
            const float mo = sm.red.cs[t][k][0], so = sm.red.cs[t][k][1];
            const float nm = fmaxf(M, mo);
            S = S * __expf(M - nm) + so * __expf(mo - nm);
            M = nm;
        }
        ((float2*)(ws + OF_PCOL))[((size_t)n * PADL + s0 + t) * TN + by] = make_float2(M, S);
    }
}

// -------------------------------------------------- combine 38 partials -----
__global__ __launch_bounds__(256) void combine_stats(float* __restrict__ ws) {
    const int idx = blockIdx.x * 256 + threadIdx.x;   // 19200 total
    const int half_ = idx >= 9600;
    const int i = idx - half_ * 9600;
    const int n = i / LS, r = i % LS;
    const float2* P = (const float2*)(ws + (half_ ? OF_PCOL : OF_PROW)) + ((size_t)n * PADL + r) * TN;
    float M = -1e30f, S = 0.f;
    for (int b = 0; b < TN; b++) {
        const float2 p = P[b];
        const float nm = fmaxf(M, p.x);
        S = S * __expf(M - nm) + p.y * __expf(p.x - nm);
        M = nm;
    }
    ((float2*)(ws + (half_ ? OF_CST : OF_RST)))[n * LS + r] = make_float2(M, 1.0f / S);
}

// ---- pass 2: recompute GEMM, write conf directly, fused row-argmax/col-max -
__global__ __launch_bounds__(512, 6) void gemm_conf(float* __restrict__ out,
                                                    float* __restrict__ ws) {
    __shared__ __align__(16) union {
        struct { _Float16 A[2][4096]; _Float16 B[2][4096]; } st;  // 32KB
        struct { float rst[128][2]; float cst[128][2];
                 float rsv[128][2][2]; float csv[128][4]; } ep;   // 6KB
    } sm;
    int n, by, bx;
    swizzle_ids(n, by, bx);
    const _Float16* Ah = (const _Float16*)(ws + OF_AH) + (size_t)n * LS * CCH;
    const _Float16* Bh = (const _Float16*)(ws + OF_BH) + (size_t)n * LS * CCH;
    const int tid = threadIdx.x;
    const int lane = tid & 63, w = tid >> 6;
    const int wx = w & 1, wy = w >> 1;
    const int m = lane & 15, quad = lane >> 4;

    f32x4 acc[2][4];
    {
        f32x4 z = {0.f, 0.f, 0.f, 0.f};
#pragma unroll
        for (int a = 0; a < 2; a++)
#pragma unroll
            for (int b = 0; b < 4; b++) acc[a][b] = z;
    }
    gemm_core(Ah, Bh, &sm.st.A[0][0], &sm.st.B[0][0], bx, by, tid, acc);

    const int l0 = by * 128, s0 = bx * 128;
    const bool full = (by < 37) & (bx < 37);
    // stage global softmax stats for this tile's rows/cols into LDS
    if (tid < 128) {
        int r = l0 + tid; r = r < LS ? r : LS - 1;
        const float2 v = ((const float2*)(ws + OF_RST))[n * LS + r];
        sm.ep.rst[tid][0] = v.x; sm.ep.rst[tid][1] = v.y;
    } else if (tid < 256) {
        const int t = tid - 128;
        int c = s0 + t; c = c < LS ? c : LS - 1;
        const float2 v = ((const float2*)(ws + OF_CST))[n * LS + c];
        sm.ep.cst[t][0] = v.x; sm.ep.cst[t][1] = v.y;
    }
    __syncthreads();

    float* On = out + (size_t)n * LS * LS;
    float colm[4] = {-1.f, -1.f, -1.f, -1.f};
    int gc4[4]; float cmx[4], csi[4];
#pragma unroll
    for (int b = 0; b < 4; b++) {
        const int cl = wx * 64 + b * 16 + m;
        gc4[b] = s0 + cl;
        cmx[b] = sm.ep.cst[cl][0]; csi[b] = sm.ep.cst[cl][1];
    }
    if (full) {
#pragma unroll
        for (int a = 0; a < 2; a++) {
#pragma unroll
            for (int reg = 0; reg < 4; reg++) {
                const int rl = wy * 32 + a * 16 + quad * 4 + reg;
                const int gr = l0 + rl;
                const float rm = sm.ep.rst[rl][0], rsi = sm.ep.rst[rl][1];
                float bestv = -1.f; int besti = 0;
#pragma unroll
                for (int b = 0; b < 4; b++) {
                    const float c = __expf(2.f * acc[a][b][reg] - rm - cmx[b]) * (rsi * csi[b]);
                    On[(size_t)gr * LS + gc4[b]] = c;
                    if (c > bestv) { bestv = c; besti = gc4[b]; }
                    colm[b] = fmaxf(colm[b], c);
                }
#pragma unroll
                for (int d = 1; d < 16; d <<= 1) {
                    const float ov = __shfl_xor(bestv, d, 64);
                    const int oi = __shfl_xor(besti, d, 64);
                    if (ov > bestv || (ov == bestv && oi < besti)) { bestv = ov; besti = oi; }
                }
                if (m == 0) {
                    sm.ep.rsv[rl][wx][0] = bestv;
                    sm.ep.rsv[rl][wx][1] = __int_as_float(besti);
                }
            }
        }
    } else {
        bool bval[4];
#pragma unroll
        for (int b = 0; b < 4; b++) bval[b] = gc4[b] < LS;
#pragma unroll
        for (int a = 0; a < 2; a++) {
#pragma unroll
            for (int reg = 0; reg < 4; reg++) {
                const int rl = wy * 32 + a * 16 + quad * 4 + reg;
                const int gr = l0 + rl;
                const float rm = sm.ep.rst[rl][0], rsi = sm.ep.rst[rl][1];
                const bool rv = gr < LS;
                float bestv = -1.f; int besti = 0;
#pragma unroll
                for (int b = 0; b < 4; b++) {
                    const float c = __expf(2.f * acc[a][b][reg] - rm - cmx[b]) * (rsi * csi[b]);
                    if (rv && bval[b]) {
                        On[(size_t)gr * LS + gc4[b]] = c;
                        if (c > bestv) { bestv = c; besti = gc4[b]; }
                        colm[b] = fmaxf(colm[b], c);
                    }
                }
#pragma unroll
                for (int d = 1; d < 16; d <<= 1) {
                    const float ov = __shfl_xor(bestv, d, 64);
                    const int oi = __shfl_xor(besti, d, 64);
                    if (ov > bestv || (ov == bestv && oi < besti)) { bestv = ov; besti = oi; }
                }
                if (m == 0) {
                    sm.ep.rsv[rl][wx][0] = bestv;
                    sm.ep.rsv[rl][wx][1] = __int_as_float(besti);
                }
            }
        }
    }
#pragma unroll
    for (int b = 0; b < 4; b++) {
        float v = colm[b];
        v = fmaxf(v, __shfl_xor(v, 16, 64));
        v = fmaxf(v, __shfl_xor(v, 32, 64));
        if (quad == 0) sm.ep.csv[wx * 64 + b * 16 + m][wy] = v;
    }
    __syncthreads();
    if (tid < 128) {
        const float v0 = sm.ep.rsv[tid][0][0]; const int i0 = __float_as_int(sm.ep.rsv[tid][0][1]);
        const float v1 = sm.ep.rsv[tid][1][0]; const int i1 = __float_as_int(sm.ep.rsv[tid][1][1]);
        float bv; int bi;
        if (v0 > v1 || (v0 == v1 && i0 <= i1)) { bv = v0; bi = i0; } else { bv = v1; bi = i1; }
        ((float2*)(ws + OF_PROW))[((size_t)n * PADL + l0 + tid) * TN + bx] =
            make_float2(bv, __int_as_float(bi));
    } else if (tid < 256) {
        const int t = tid - 128;
        const float v = fmaxf(fmaxf(sm.ep.csv[t][0], sm.ep.csv[t][1]),
                              fmaxf(sm.ep.csv[t][2], sm.ep.csv[t][3]));
        (ws + OF_PCOL)[((size_t)n * PADL + s0 + t) * TN + by] = v;
    }
}

// ------------------------------------------- combine 38 max partials --------
__global__ __launch_bounds__(256) void combine_max(float* __restrict__ ws) {
    const int idx = blockIdx.x * 256 + threadIdx.x;   // 19200 total
    const int half_ = idx >= 9600;
    const int i = idx - half_ * 9600;
    const int n = i / LS, r = i % LS;
    if (!half_) {
        const float2* P = (const float2*)(ws + OF_PROW) + ((size_t)n * PADL + r) * TN;
        float bv = -2.f; int bi = 0;
        for (int b = 0; b < TN; b++) {
            const float2 p = P[b];
            const int pi = __float_as_int(p.y);
            if (p.x > bv || (p.x == bv && pi < bi)) { bv = p.x; bi = pi; }
        }
        ws[OF_RWM + i] = bv;
        ((int*)ws)[OF_CAND + i] = bi;
    } else {
        const float* P = ws + OF_PCOL + ((size_t)n * PADL + r) * TN;
        float v = -2.f;
        for (int b = 0; b < TN; b++) v = fmaxf(v, P[b]);
        ws[OF_CLM + i] = v;
    }
}

// ------------------------------------------------------------- matching -----
__global__ __launch_bounds__(256) void match_pass(const float* __restrict__ ws,
                                                  float* __restrict__ out) {
    const int idx = blockIdx.x * 256 + threadIdx.x;
    if (idx >= NB * LS) return;
    const int n = idx / LS, l = idx % LS;
    const float rwm = ws[OF_RWM + idx];
    const int cand = ((const int*)ws)[OF_CAND + idx];
    const float clm = ws[OF_CLM + n * LS + cand];
    const int y0 = l / W0, x0 = l % W0;
    const int y1 = cand / W1, x1 = cand % W1;
    const bool b0 = (y0 >= 2 && y0 < 58 && x0 >= 2 && x0 < 78);
    const bool b1 = (y1 >= 2 && y1 < 58 && x1 >= 2 && x1 < 78);
    const bool matched = (rwm > THRV) && b0 && b1 && (rwm == clm);
    const int j = matched ? cand : 0;
    out[O_MASKV + idx] = matched ? 1.f : 0.f;
    out[O_JIDS + idx] = (float)j;
    out[O_MKPT + (size_t)idx * 2 + 0] = (float)(j % W1);
    out[O_MKPT + (size_t)idx * 2 + 1] = (float)(j / W1);
    out[O_MCONF + idx] = matched ? rwm : 0.f;
}

// -------------------------------------------------------------- launch ------
extern "C" void kernel_launch(void* const* d_in, const int* in_sizes, int n_in,
                              void* d_out, int out_size, void* d_ws, size_t ws_size,
                              hipStream_t stream) {
    const float* f0 = (const float*)d_in[0];
    const float* f1 = (const float*)d_in[1];
    float* out = (float*)d_out;
    float* ws = (float*)d_ws;

    conv_half<<<dim3(2400, 2), 256, 0, stream>>>(f0, f1, ws);
    gemm_stats<<<dim3(TN, TN, NB), 512, 0, stream>>>(ws);
    combine_stats<<<75, 256, 0, stream>>>(ws);
    gemm_conf<<<dim3(TN, TN, NB), 512, 0, stream>>>(out, ws);
    combine_max<<<75, 256, 0, stream>>>(ws);
    match_pass<<<38, 256, 0, stream>>>(ws, out);
}